// Round 6
// baseline (185.091 us; speedup 1.0000x reference)
//
#include <hip/hip_runtime.h>

// ---------------------------------------------------------------------------
// Causal MHSA. B=2, T=2048, D=1024, H=16, hd=64. fp32 in -> bf16 internal ->
// fp32 out. R17: attn/canon = R16 exact (47.7us attn). Both GEMMs get the
// minimum 2-phase double-buffer (T3-lite): stage tile t+1 via global_load_lds
// BEFORE compute of tile t, ONE __syncthreads per K-step (was 2) — load
// latency covered by the MFMA span instead of a bare drain. BK=32 kept
// (proven); LDS qkv 32KB / out 24KB.
// ---------------------------------------------------------------------------

#define T_SEQ 2048
#define D_MODEL 1024
#define NEG_BIG (-1.0e30f)
#define Q_SCALE 0.18033688f   // 0.125 * log2(e): attention uses exp2 directly

typedef float f32x4 __attribute__((ext_vector_type(4)));
typedef short s16x8 __attribute__((ext_vector_type(8)));
typedef __bf16 bf16x8 __attribute__((ext_vector_type(8)));

__device__ __forceinline__ f32x4 mfma16(s16x8 a, s16x8 b, f32x4 c) {
    // C[m][n]=sum_k A[m][k]B[n][k]; lane: a=A[m=l16][k=quad*8+j],
    // b=B[n=l16][k=quad*8+j]; C: col(l16)=n, row(quad*4+r)=m
    return __builtin_amdgcn_mfma_f32_16x16x32_bf16(
        __builtin_bit_cast(bf16x8, a), __builtin_bit_cast(bf16x8, b), c, 0, 0, 0);
}

__device__ __forceinline__ short f2bf(float f) {          // RNE
    unsigned int u = __float_as_uint(f);
    u += 0x7fffu + ((u >> 16) & 1u);
    return (short)(u >> 16);
}
__device__ __forceinline__ float bf2f(short s) {
    return __uint_as_float(((unsigned int)(unsigned short)s) << 16);
}
__device__ __forceinline__ unsigned cvt_pk_bf16(float lo, float hi) {
    unsigned r;
    asm("v_cvt_pk_bf16_f32 %0, %1, %2" : "=v"(r) : "v"(lo), "v"(hi));
    return r;
}

__device__ __forceinline__ void async_lds16(const short* g, short* l) {
    __builtin_amdgcn_global_load_lds(
        (const __attribute__((address_space(1))) unsigned int*)g,
        (__attribute__((address_space(3))) unsigned int*)l, 16, 0, 0);
}

// ---------------------------------------------------------------------------
// Fused canon: five fp32 inputs -> bf16, float4-vectorized, one launch.
// ---------------------------------------------------------------------------
#define N_X   4194304
#define N_WI  3145728
#define N_BI  3072
#define N_WO  1048576
#define N_BO  1024
#define V_X   (N_X  / 4)
#define V_WI  (N_WI / 4)
#define V_BI  (N_BI / 4)
#define V_WO  (N_WO / 4)
#define V_BO  (N_BO / 4)
#define V_TOT (V_X + V_WI + V_BI + V_WO + V_BO)

__global__ __launch_bounds__(256) void canon_all_kernel(
    const float* __restrict__ x, const float* __restrict__ wi,
    const float* __restrict__ bi, const float* __restrict__ wo,
    const float* __restrict__ bo,
    short* __restrict__ xb, short* __restrict__ wib, short* __restrict__ bib,
    short* __restrict__ wob, short* __restrict__ bob)
{
    int i = blockIdx.x * 256 + threadIdx.x;
    if (i >= V_TOT) return;
    const float* src; short* dst; int off;
    if      (i < V_X)                    { src = x;  dst = xb;  off = i; }
    else if (i < V_X+V_WI)               { src = wi; dst = wib; off = i - V_X; }
    else if (i < V_X+V_WI+V_BI)          { src = bi; dst = bib; off = i - V_X - V_WI; }
    else if (i < V_X+V_WI+V_BI+V_WO)     { src = wo; dst = wob; off = i - V_X - V_WI - V_BI; }
    else                                 { src = bo; dst = bob; off = i - V_X - V_WI - V_BI - V_WO; }
    float4 v = ((const float4*)src)[off];
    short4 o = { f2bf(v.x), f2bf(v.y), f2bf(v.z), f2bf(v.w) };
    ((short4*)dst)[off] = o;
}

// ---------------------------------------------------------------------------
// GEMM1 (BK=32, 2-phase dbuf): qkv = x @ w_in^T + b_in.
// q(xQ_SCALE)/k -> [B,H,T,64]; v -> Vt [B,H,64,T] (transpose fused).
// ---------------------------------------------------------------------------
__global__ __launch_bounds__(256) void gemm_qkv_kernel(
    const short* __restrict__ A, const short* __restrict__ B,
    const short* __restrict__ bias,
    short* __restrict__ qo, short* __restrict__ ko, short* __restrict__ vto)
{
    const int K = 1024;
    alignas(16) __shared__ short As[2][128][32];
    alignas(16) __shared__ short Bs[2][128][32];
    const int m0 = blockIdx.x * 128;
    const int n0 = blockIdx.y * 128;
    const int tid = threadIdx.x;
    const int lane = tid & 63;
    const int w = tid >> 6;
    const int wm = (w >> 1) * 64, wn = (w & 1) * 64;
    const int quad = lane >> 4, l16 = lane & 15;

    f32x4 acc[4][4];
    const f32x4 zero = {0.f, 0.f, 0.f, 0.f};
#pragma unroll
    for (int i = 0; i < 4; ++i)
#pragma unroll
        for (int j = 0; j < 4; ++j) acc[i][j] = zero;

    const int lrow = lane >> 2;
    const int lcol = (lane & 3) * 8;
    const short* gA0 = &A[(m0 + w*32      + lrow) * K + lcol];
    const short* gA1 = &A[(m0 + w*32 + 16 + lrow) * K + lcol];
    const short* gB0 = &B[(n0 + w*32      + lrow) * K + lcol];
    const short* gB1 = &B[(n0 + w*32 + 16 + lrow) * K + lcol];

#define QKV_STAGE(buf, koff)                                   \
    do {                                                       \
        short* dA = &As[(buf)][w*32][0];                       \
        short* dB = &Bs[(buf)][w*32][0];                       \
        async_lds16(gA0 + (koff), dA);                         \
        async_lds16(gA1 + (koff), dA + 16*32);                 \
        async_lds16(gB0 + (koff), dB);                         \
        async_lds16(gB1 + (koff), dB + 16*32);                 \
    } while (0)

    QKV_STAGE(0, 0);
    int cur = 0;
    for (int k0 = 0; k0 < K; k0 += 32) {
        __syncthreads();                       // drains: buf[cur] ready; buf[cur^1] free
        if (k0 + 32 < K) QKV_STAGE(cur ^ 1, k0 + 32);

        s16x8 af[4], bfr[4];
        const short (*Ac)[32] = As[cur];
        const short (*Bc)[32] = Bs[cur];
#pragma unroll
        for (int i = 0; i < 4; ++i) af[i]  = *(const s16x8*)&Ac[wm + i*16 + l16][quad*8];
#pragma unroll
        for (int j = 0; j < 4; ++j) bfr[j] = *(const s16x8*)&Bc[wn + j*16 + l16][quad*8];
#pragma unroll
        for (int i = 0; i < 4; ++i)
#pragma unroll
            for (int j = 0; j < 4; ++j)
                acc[i][j] = mfma16(af[i], bfr[j], acc[i][j]);
        cur ^= 1;
    }
#undef QKV_STAGE

#pragma unroll
    for (int j = 0; j < 4; ++j) {
        int n = n0 + wn + j*16 + l16;
        float bi = bf2f(bias[n]);
        int which = n >> 10;            // wave-uniform (16 consecutive n)
        int h = (n >> 6) & 15, d = n & 63;
        if (which < 2) {                // Q / K: [B,H,T,64]
            short* dst = (which == 0) ? qo : ko;
            float scl = (which == 0) ? Q_SCALE : 1.0f;
#pragma unroll
            for (int i = 0; i < 4; ++i) {
#pragma unroll
                for (int r = 0; r < 4; ++r) {
                    int m = m0 + wm + i*16 + quad*4 + r;
                    int b = m >> 11, t = m & 2047;
                    float v = (acc[i][j][r] + bi) * scl;
                    dst[(((b*16 + h) * 2048) + t) * 64 + d] = f2bf(v);
                }
            }
        } else {                        // V: write transposed [B,H,64,T]
#pragma unroll
            for (int i = 0; i < 4; ++i) {
                int m = m0 + wm + i*16 + quad*4;   // t0, %4 == 0
                int b = m >> 11, t0 = m & 2047;
                short4 o4 = { f2bf(acc[i][j][0] + bi), f2bf(acc[i][j][1] + bi),
                              f2bf(acc[i][j][2] + bi), f2bf(acc[i][j][3] + bi) };
                *(short4*)&vto[(((size_t)(b*16 + h) * 64) + d) * 2048 + t0] = o4;
            }
        }
    }
}

// ---------------------------------------------------------------------------
// Flash attention — R11 exact structure & mapping (proven 48.2us):
// dim3(32,32), bh=blockIdx.x (XCD=bh%8 L2 locality), qt=31-blockIdx.y
// (heavy-first). cvt_pk_bf16 packing (T12) for P and O (R15, -0.5us).
// ---------------------------------------------------------------------------
__global__ __launch_bounds__(256) void attn_kernel(
    const short* __restrict__ Q, const short* __restrict__ K,
    const short* __restrict__ Vt, short* __restrict__ ctx)
{
    alignas(16) __shared__ short Ks[64][72];      // [s][d]
    alignas(16) __shared__ short Vs[64][72];      // [d][s]
    alignas(16) __shared__ short Pl[4][16][72];   // per-wave [q][s]

    const int bh = blockIdx.x;
    const int qt = 31 - (int)blockIdx.y;          // heavy tiles first
    const int qbase = qt * 64;
    const int tid = threadIdx.x;
    const int w = tid >> 6, lane = tid & 63;
    const int quad = lane >> 4, l16 = lane & 15;
    const int b = bh >> 4, h = bh & 15;

    const short* Qb  = Q  + bh * T_SEQ * 64;
    const short* Kb  = K  + bh * T_SEQ * 64;
    const short* Vbt = Vt + (size_t)bh * 64 * T_SEQ;

    const short* qrow = Qb + (qbase + w*16 + l16) * 64;
    const s16x8 qa0 = *(const s16x8*)(qrow + quad*8);
    const s16x8 qa1 = *(const s16x8*)(qrow + 32 + quad*8);

    const f32x4 zero = {0.f, 0.f, 0.f, 0.f};
    f32x4 o[4];
#pragma unroll
    for (int dt = 0; dt < 4; ++dt) o[dt] = zero;
    float lsum = 0.f;

    const int sr  = tid >> 3;                     // 0..31
    const int scl = (tid & 7) * 8;                // 0..56
    const int qg  = qbase + w*16 + l16;

    // preload tile s0=0
    float4 kf0 = *(const float4*)&Kb[sr * 64 + scl];
    float4 kf1 = *(const float4*)&Kb[(sr + 32) * 64 + scl];
    float4 vf0 = *(const float4*)&Vbt[(size_t)sr * T_SEQ + scl];
    float4 vf1 = *(const float4*)&Vbt[(size_t)(sr + 32) * T_SEQ + scl];

    for (int s0 = 0; s0 <= qbase; s0 += 64) {
        __syncthreads();
        *(float4*)&Ks[sr][scl]    = kf0;
        *(float4*)&Ks[sr+32][scl] = kf1;
        *(float4*)&Vs[sr][scl]    = vf0;
        *(float4*)&Vs[sr+32][scl] = vf1;
        __syncthreads();

        if (s0 + 64 <= qbase) {                   // prefetch next tile
            kf0 = *(const float4*)&Kb[(s0 + 64 + sr) * 64 + scl];
            kf1 = *(const float4*)&Kb[(s0 + 64 + sr + 32) * 64 + scl];
            vf0 = *(const float4*)&Vbt[(size_t)sr * T_SEQ + s0 + 64 + scl];
            vf1 = *(const float4*)&Vbt[(size_t)(sr + 32) * T_SEQ + s0 + 64 + scl];
        }

        // S^T = K Q^T
#pragma unroll
        for (int sub = 0; sub < 4; ++sub) {
            s16x8 ka0 = *(const s16x8*)&Ks[sub*16 + l16][quad*8];
            s16x8 ka1 = *(const s16x8*)&Ks[sub*16 + l16][32 + quad*8];
            f32x4 S = mfma16(ka1, qa1, mfma16(ka0, qa0, zero));
            if (s0 == qbase) {                    // diagonal: causal mask
                int sb = s0 + sub*16 + quad*4;
#pragma unroll
                for (int r = 0; r < 4; ++r)
                    if (sb + r > qg) S[r] = NEG_BIG;
            }
            float p0 = exp2f(S[0]), p1 = exp2f(S[1]);
            float p2 = exp2f(S[2]), p3 = exp2f(S[3]);
            lsum += (p0 + p1) + (p2 + p3);
            uint2 pk;
            pk.x = cvt_pk_bf16(p0, p1);
            pk.y = cvt_pk_bf16(p2, p3);
            *(uint2*)&Pl[w][l16][sub*16 + quad*4] = pk;
        }
        // wave-private Pl: in-order within wave, no barrier

        // O^T += V^T P^T
        s16x8 pb0 = *(const s16x8*)&Pl[w][l16][quad*8];
        s16x8 pb1 = *(const s16x8*)&Pl[w][l16][32 + quad*8];
#pragma unroll
        for (int dt = 0; dt < 4; ++dt) {
            s16x8 va0 = *(const s16x8*)&Vs[dt*16 + l16][quad*8];
            s16x8 va1 = *(const s16x8*)&Vs[dt*16 + l16][32 + quad*8];
            o[dt] = mfma16(va1, pb1, mfma16(va0, pb0, o[dt]));
        }
    }

    lsum += __shfl_xor(lsum, 16, 64);
    lsum += __shfl_xor(lsum, 32, 64);
    float inv = 1.0f / lsum;
    int base = (b * T_SEQ + qg) * D_MODEL + h * 64;
#pragma unroll
    for (int dt = 0; dt < 4; ++dt) {
        uint2 pk;
        pk.x = cvt_pk_bf16(o[dt][0] * inv, o[dt][1] * inv);
        pk.y = cvt_pk_bf16(o[dt][2] * inv, o[dt][3] * inv);
        *(uint2*)&ctx[base + dt*16 + quad*4] = pk;
    }
}

// ---------------------------------------------------------------------------
// GEMM2 (BK=32, 2-phase dbuf): out = ctx @ w_out^T + b_out, fp32 store.
// 128x64, 512 blocks.
// ---------------------------------------------------------------------------
__global__ __launch_bounds__(256) void gemm_out_kernel(
    const short* __restrict__ A, const short* __restrict__ B,
    const short* __restrict__ bias, float* __restrict__ out)
{
    const int K = 1024;
    alignas(16) __shared__ short As[2][128][32];
    alignas(16) __shared__ short Bs[2][64][32];
    const int m0 = blockIdx.x * 128;
    const int n0 = blockIdx.y * 64;
    const int tid = threadIdx.x;
    const int lane = tid & 63;
    const int w = tid >> 6;
    const int wm = (w >> 1) * 64, wn = (w & 1) * 32;
    const int quad = lane >> 4, l16 = lane & 15;

    f32x4 acc[4][2];
    const f32x4 zero = {0.f, 0.f, 0.f, 0.f};
#pragma unroll
    for (int i = 0; i < 4; ++i)
#pragma unroll
        for (int j = 0; j < 2; ++j) acc[i][j] = zero;

    const int lrow = lane >> 2;
    const int lcol = (lane & 3) * 8;
    const short* gA0 = &A[(m0 + w*32      + lrow) * K + lcol];
    const short* gA1 = &A[(m0 + w*32 + 16 + lrow) * K + lcol];
    const short* gB0 = &B[(n0 + w*16 + lrow) * K + lcol];

#define OUT_STAGE(buf, koff)                                   \
    do {                                                       \
        short* dA = &As[(buf)][w*32][0];                       \
        short* dB = &Bs[(buf)][w*16][0];                       \
        async_lds16(gA0 + (koff), dA);                         \
        async_lds16(gA1 + (koff), dA + 16*32);                 \
        async_lds16(gB0 + (koff), dB);                         \
    } while (0)

    OUT_STAGE(0, 0);
    int cur = 0;
    for (int k0 = 0; k0 < K; k0 += 32) {
        __syncthreads();
        if (k0 + 32 < K) OUT_STAGE(cur ^ 1, k0 + 32);

        s16x8 af[4], bfr[2];
        const short (*Ac)[32] = As[cur];
        const short (*Bc)[32] = Bs[cur];
#pragma unroll
        for (int i = 0; i < 4; ++i) af[i]  = *(const s16x8*)&Ac[wm + i*16 + l16][quad*8];
#pragma unroll
        for (int j = 0; j < 2; ++j) bfr[j] = *(const s16x8*)&Bc[wn + j*16 + l16][quad*8];
#pragma unroll
        for (int i = 0; i < 4; ++i)
#pragma unroll
            for (int j = 0; j < 2; ++j)
                acc[i][j] = mfma16(af[i], bfr[j], acc[i][j]);
        cur ^= 1;
    }
#undef OUT_STAGE

#pragma unroll
    for (int j = 0; j < 2; ++j) {
        int n = n0 + wn + j*16 + l16;
        float bi = bf2f(bias[n]);
#pragma unroll
        for (int i = 0; i < 4; ++i) {
#pragma unroll
            for (int r = 0; r < 4; ++r) {
                int m = m0 + wm + i*16 + quad*4 + r;
                out[m * 1024 + n] = acc[i][j][r] + bi;
            }
        }
    }
}

// ---------------------------------------------------------------------------
extern "C" void kernel_launch(void* const* d_in, const int* in_sizes, int n_in,
                              void* d_out, int out_size, void* d_ws, size_t ws_size,
                              hipStream_t stream) {
    float* out = (float*)d_out;
    char* ws = (char*)d_ws;

    const size_t MB = 1u << 20;
    short* xb     = (short*)(ws);            // 8 MB
    short* w_inb  = (short*)(ws + 8*MB);     // 6 MB
    short* b_inb  = (short*)(ws + 14*MB);
    short* w_outb = (short*)(ws + 15*MB);    // 2 MB
    short* b_outb = (short*)(ws + 17*MB);
    short* qb     = (short*)(ws + 18*MB);    // 8 MB [B,H,T,64]
    short* kb     = (short*)(ws + 26*MB);    // 8 MB [B,H,T,64]
    short* vtb    = (short*)(ws + 34*MB);    // 8 MB [B,H,64,T] (direct from gemm)
    short* ctxb   = (short*)(ws + 42*MB);    // 8 MB [B,T,D]

    canon_all_kernel<<<(V_TOT + 255) / 256, 256, 0, stream>>>(
        (const float*)d_in[0], (const float*)d_in[1], (const float*)d_in[2],
        (const float*)d_in[3], (const float*)d_in[4],
        xb, w_inb, b_inb, w_outb, b_outb);

    gemm_qkv_kernel<<<dim3(32, 24), 256, 0, stream>>>(xb, w_inb, b_inb, qb, kb, vtb);
    attn_kernel<<<dim3(32, 32), 256, 0, stream>>>(qb, kb, vtb, ctxb);
    gemm_out_kernel<<<dim3(32, 16), 256, 0, stream>>>(ctxb, w_outb, b_outb, out);
}

// Round 7
// 175.396 us; speedup vs baseline: 1.0553x; 1.0553x over previous
//
#include <hip/hip_runtime.h>

// ---------------------------------------------------------------------------
// Causal MHSA. B=2, T=2048, D=1024, H=16, hd=64. fp32 in -> bf16 internal ->
// fp32 out. R18: GEMMs/canon reverted to R16 exact (non-attn 126.6us best;
// R15 BK=64 and R17 2-phase dbuf both measured regressions — 128^2 m97
// 2-barrier structure is the local optimum, matching learn_hip m230-vs-m97).
// attn: R16 + T5 s_setprio(1) around MFMA clusters (m191 regime: independent
// blocks give wave role diversity; predicted -2..-3us).
// ---------------------------------------------------------------------------

#define T_SEQ 2048
#define D_MODEL 1024
#define NEG_BIG (-1.0e30f)
#define Q_SCALE 0.18033688f   // 0.125 * log2(e): attention uses exp2 directly

typedef float f32x4 __attribute__((ext_vector_type(4)));
typedef short s16x8 __attribute__((ext_vector_type(8)));
typedef __bf16 bf16x8 __attribute__((ext_vector_type(8)));

__device__ __forceinline__ f32x4 mfma16(s16x8 a, s16x8 b, f32x4 c) {
    // C[m][n]=sum_k A[m][k]B[n][k]; lane: a=A[m=l16][k=quad*8+j],
    // b=B[n=l16][k=quad*8+j]; C: col(l16)=n, row(quad*4+r)=m
    return __builtin_amdgcn_mfma_f32_16x16x32_bf16(
        __builtin_bit_cast(bf16x8, a), __builtin_bit_cast(bf16x8, b), c, 0, 0, 0);
}

__device__ __forceinline__ short f2bf(float f) {          // RNE
    unsigned int u = __float_as_uint(f);
    u += 0x7fffu + ((u >> 16) & 1u);
    return (short)(u >> 16);
}
__device__ __forceinline__ float bf2f(short s) {
    return __uint_as_float(((unsigned int)(unsigned short)s) << 16);
}
__device__ __forceinline__ unsigned cvt_pk_bf16(float lo, float hi) {
    unsigned r;
    asm("v_cvt_pk_bf16_f32 %0, %1, %2" : "=v"(r) : "v"(lo), "v"(hi));
    return r;
}

__device__ __forceinline__ void async_lds16(const short* g, short* l) {
    __builtin_amdgcn_global_load_lds(
        (const __attribute__((address_space(1))) unsigned int*)g,
        (__attribute__((address_space(3))) unsigned int*)l, 16, 0, 0);
}

// ---------------------------------------------------------------------------
// Fused canon: five fp32 inputs -> bf16, float4-vectorized, one launch.
// ---------------------------------------------------------------------------
#define N_X   4194304
#define N_WI  3145728
#define N_BI  3072
#define N_WO  1048576
#define N_BO  1024
#define V_X   (N_X  / 4)
#define V_WI  (N_WI / 4)
#define V_BI  (N_BI / 4)
#define V_WO  (N_WO / 4)
#define V_BO  (N_BO / 4)
#define V_TOT (V_X + V_WI + V_BI + V_WO + V_BO)

__global__ __launch_bounds__(256) void canon_all_kernel(
    const float* __restrict__ x, const float* __restrict__ wi,
    const float* __restrict__ bi, const float* __restrict__ wo,
    const float* __restrict__ bo,
    short* __restrict__ xb, short* __restrict__ wib, short* __restrict__ bib,
    short* __restrict__ wob, short* __restrict__ bob)
{
    int i = blockIdx.x * 256 + threadIdx.x;
    if (i >= V_TOT) return;
    const float* src; short* dst; int off;
    if      (i < V_X)                    { src = x;  dst = xb;  off = i; }
    else if (i < V_X+V_WI)               { src = wi; dst = wib; off = i - V_X; }
    else if (i < V_X+V_WI+V_BI)          { src = bi; dst = bib; off = i - V_X - V_WI; }
    else if (i < V_X+V_WI+V_BI+V_WO)     { src = wo; dst = wob; off = i - V_X - V_WI - V_BI; }
    else                                 { src = bo; dst = bob; off = i - V_X - V_WI - V_BI - V_WO; }
    float4 v = ((const float4*)src)[off];
    short4 o = { f2bf(v.x), f2bf(v.y), f2bf(v.z), f2bf(v.w) };
    ((short4*)dst)[off] = o;
}

// ---------------------------------------------------------------------------
// GEMM1 (m97 structure, BK=32): qkv = x @ w_in^T + b_in.
// q(xQ_SCALE)/k -> [B,H,T,64]; v -> Vt [B,H,64,T] (transpose fused: the
// r-loop's 4 acc values are t-consecutive -> one aligned short4 store).
// ---------------------------------------------------------------------------
__global__ __launch_bounds__(256) void gemm_qkv_kernel(
    const short* __restrict__ A, const short* __restrict__ B,
    const short* __restrict__ bias,
    short* __restrict__ qo, short* __restrict__ ko, short* __restrict__ vto)
{
    const int K = 1024;
    alignas(16) __shared__ short As[128][32];
    alignas(16) __shared__ short Bs[128][32];
    const int m0 = blockIdx.x * 128;
    const int n0 = blockIdx.y * 128;
    const int tid = threadIdx.x;
    const int lane = tid & 63;
    const int w = tid >> 6;
    const int wm = (w >> 1) * 64, wn = (w & 1) * 64;
    const int quad = lane >> 4, l16 = lane & 15;

    f32x4 acc[4][4];
    const f32x4 zero = {0.f, 0.f, 0.f, 0.f};
#pragma unroll
    for (int i = 0; i < 4; ++i)
#pragma unroll
        for (int j = 0; j < 4; ++j) acc[i][j] = zero;

    const int lrow = lane >> 2;
    const int lcol = (lane & 3) * 8;
    const short* gA0 = &A[(m0 + w*32      + lrow) * K + lcol];
    const short* gA1 = &A[(m0 + w*32 + 16 + lrow) * K + lcol];
    const short* gB0 = &B[(n0 + w*32      + lrow) * K + lcol];
    const short* gB1 = &B[(n0 + w*32 + 16 + lrow) * K + lcol];
    short* lA0 = &As[w*32][0];
    short* lA1 = &As[w*32 + 16][0];
    short* lB0 = &Bs[w*32][0];
    short* lB1 = &Bs[w*32 + 16][0];

    for (int k0 = 0; k0 < K; k0 += 32) {
        __syncthreads();
        async_lds16(gA0 + k0, lA0);
        async_lds16(gA1 + k0, lA1);
        async_lds16(gB0 + k0, lB0);
        async_lds16(gB1 + k0, lB1);
        __syncthreads();

        s16x8 af[4], bfr[4];
#pragma unroll
        for (int i = 0; i < 4; ++i) af[i]  = *(const s16x8*)&As[wm + i*16 + l16][quad*8];
#pragma unroll
        for (int j = 0; j < 4; ++j) bfr[j] = *(const s16x8*)&Bs[wn + j*16 + l16][quad*8];
#pragma unroll
        for (int i = 0; i < 4; ++i)
#pragma unroll
            for (int j = 0; j < 4; ++j)
                acc[i][j] = mfma16(af[i], bfr[j], acc[i][j]);
    }

#pragma unroll
    for (int j = 0; j < 4; ++j) {
        int n = n0 + wn + j*16 + l16;
        float bi = bf2f(bias[n]);
        int which = n >> 10;            // wave-uniform (16 consecutive n)
        int h = (n >> 6) & 15, d = n & 63;
        if (which < 2) {                // Q / K: [B,H,T,64]
            short* dst = (which == 0) ? qo : ko;
            float scl = (which == 0) ? Q_SCALE : 1.0f;
#pragma unroll
            for (int i = 0; i < 4; ++i) {
#pragma unroll
                for (int r = 0; r < 4; ++r) {
                    int m = m0 + wm + i*16 + quad*4 + r;
                    int b = m >> 11, t = m & 2047;
                    float v = (acc[i][j][r] + bi) * scl;
                    dst[(((b*16 + h) * 2048) + t) * 64 + d] = f2bf(v);
                }
            }
        } else {                        // V: write transposed [B,H,64,T]
#pragma unroll
            for (int i = 0; i < 4; ++i) {
                int m = m0 + wm + i*16 + quad*4;   // t0, %4 == 0
                int b = m >> 11, t0 = m & 2047;
                short4 o4 = { f2bf(acc[i][j][0] + bi), f2bf(acc[i][j][1] + bi),
                              f2bf(acc[i][j][2] + bi), f2bf(acc[i][j][3] + bi) };
                *(short4*)&vto[(((size_t)(b*16 + h) * 64) + d) * 2048 + t0] = o4;
            }
        }
    }
}

// ---------------------------------------------------------------------------
// Flash attention — R11 structure & mapping (dim3(32,32), bh=blockIdx.x for
// XCD=bh%8 L2 locality, qt=31-y heavy-first), cvt_pk packing (R15), plus
// T5 s_setprio(1) around the MFMA clusters (independent blocks -> wave role
// diversity on each CU -> scheduler can favor MFMA-entering waves).
// ---------------------------------------------------------------------------
__global__ __launch_bounds__(256) void attn_kernel(
    const short* __restrict__ Q, const short* __restrict__ K,
    const short* __restrict__ Vt, short* __restrict__ ctx)
{
    alignas(16) __shared__ short Ks[64][72];      // [s][d]
    alignas(16) __shared__ short Vs[64][72];      // [d][s]
    alignas(16) __shared__ short Pl[4][16][72];   // per-wave [q][s]

    const int bh = blockIdx.x;
    const int qt = 31 - (int)blockIdx.y;          // heavy tiles first
    const int qbase = qt * 64;
    const int tid = threadIdx.x;
    const int w = tid >> 6, lane = tid & 63;
    const int quad = lane >> 4, l16 = lane & 15;
    const int b = bh >> 4, h = bh & 15;

    const short* Qb  = Q  + bh * T_SEQ * 64;
    const short* Kb  = K  + bh * T_SEQ * 64;
    const short* Vbt = Vt + (size_t)bh * 64 * T_SEQ;

    const short* qrow = Qb + (qbase + w*16 + l16) * 64;
    const s16x8 qa0 = *(const s16x8*)(qrow + quad*8);
    const s16x8 qa1 = *(const s16x8*)(qrow + 32 + quad*8);

    const f32x4 zero = {0.f, 0.f, 0.f, 0.f};
    f32x4 o[4];
#pragma unroll
    for (int dt = 0; dt < 4; ++dt) o[dt] = zero;
    float lsum = 0.f;

    const int sr  = tid >> 3;                     // 0..31
    const int scl = (tid & 7) * 8;                // 0..56
    const int qg  = qbase + w*16 + l16;

    // preload tile s0=0
    float4 kf0 = *(const float4*)&Kb[sr * 64 + scl];
    float4 kf1 = *(const float4*)&Kb[(sr + 32) * 64 + scl];
    float4 vf0 = *(const float4*)&Vbt[(size_t)sr * T_SEQ + scl];
    float4 vf1 = *(const float4*)&Vbt[(size_t)(sr + 32) * T_SEQ + scl];

    for (int s0 = 0; s0 <= qbase; s0 += 64) {
        __syncthreads();
        *(float4*)&Ks[sr][scl]    = kf0;
        *(float4*)&Ks[sr+32][scl] = kf1;
        *(float4*)&Vs[sr][scl]    = vf0;
        *(float4*)&Vs[sr+32][scl] = vf1;
        __syncthreads();

        if (s0 + 64 <= qbase) {                   // prefetch next tile
            kf0 = *(const float4*)&Kb[(s0 + 64 + sr) * 64 + scl];
            kf1 = *(const float4*)&Kb[(s0 + 64 + sr + 32) * 64 + scl];
            vf0 = *(const float4*)&Vbt[(size_t)sr * T_SEQ + s0 + 64 + scl];
            vf1 = *(const float4*)&Vbt[(size_t)(sr + 32) * T_SEQ + s0 + 64 + scl];
        }

        // S^T = K Q^T
#pragma unroll
        for (int sub = 0; sub < 4; ++sub) {
            s16x8 ka0 = *(const s16x8*)&Ks[sub*16 + l16][quad*8];
            s16x8 ka1 = *(const s16x8*)&Ks[sub*16 + l16][32 + quad*8];
            __builtin_amdgcn_s_setprio(1);
            f32x4 S = mfma16(ka1, qa1, mfma16(ka0, qa0, zero));
            __builtin_amdgcn_s_setprio(0);
            if (s0 == qbase) {                    // diagonal: causal mask
                int sb = s0 + sub*16 + quad*4;
#pragma unroll
                for (int r = 0; r < 4; ++r)
                    if (sb + r > qg) S[r] = NEG_BIG;
            }
            float p0 = exp2f(S[0]), p1 = exp2f(S[1]);
            float p2 = exp2f(S[2]), p3 = exp2f(S[3]);
            lsum += (p0 + p1) + (p2 + p3);
            uint2 pk;
            pk.x = cvt_pk_bf16(p0, p1);
            pk.y = cvt_pk_bf16(p2, p3);
            *(uint2*)&Pl[w][l16][sub*16 + quad*4] = pk;
        }
        // wave-private Pl: in-order within wave, no barrier

        // O^T += V^T P^T
        s16x8 pb0 = *(const s16x8*)&Pl[w][l16][quad*8];
        s16x8 pb1 = *(const s16x8*)&Pl[w][l16][32 + quad*8];
        __builtin_amdgcn_s_setprio(1);
#pragma unroll
        for (int dt = 0; dt < 4; ++dt) {
            s16x8 va0 = *(const s16x8*)&Vs[dt*16 + l16][quad*8];
            s16x8 va1 = *(const s16x8*)&Vs[dt*16 + l16][32 + quad*8];
            o[dt] = mfma16(va1, pb1, mfma16(va0, pb0, o[dt]));
        }
        __builtin_amdgcn_s_setprio(0);
    }

    lsum += __shfl_xor(lsum, 16, 64);
    lsum += __shfl_xor(lsum, 32, 64);
    float inv = 1.0f / lsum;
    int base = (b * T_SEQ + qg) * D_MODEL + h * 64;
#pragma unroll
    for (int dt = 0; dt < 4; ++dt) {
        uint2 pk;
        pk.x = cvt_pk_bf16(o[dt][0] * inv, o[dt][1] * inv);
        pk.y = cvt_pk_bf16(o[dt][2] * inv, o[dt][3] * inv);
        *(uint2*)&ctx[base + dt*16 + quad*4] = pk;
    }
}

// ---------------------------------------------------------------------------
// GEMM2 (BK=32): out = ctx @ w_out^T + b_out, fp32 store. 128x64, 512 blocks.
// ---------------------------------------------------------------------------
__global__ __launch_bounds__(256) void gemm_out_kernel(
    const short* __restrict__ A, const short* __restrict__ B,
    const short* __restrict__ bias, float* __restrict__ out)
{
    const int K = 1024;
    alignas(16) __shared__ short As[128][32];
    alignas(16) __shared__ short Bs[64][32];
    const int m0 = blockIdx.x * 128;
    const int n0 = blockIdx.y * 64;
    const int tid = threadIdx.x;
    const int lane = tid & 63;
    const int w = tid >> 6;
    const int wm = (w >> 1) * 64, wn = (w & 1) * 32;
    const int quad = lane >> 4, l16 = lane & 15;

    f32x4 acc[4][2];
    const f32x4 zero = {0.f, 0.f, 0.f, 0.f};
#pragma unroll
    for (int i = 0; i < 4; ++i)
#pragma unroll
        for (int j = 0; j < 2; ++j) acc[i][j] = zero;

    const int lrow = lane >> 2;
    const int lcol = (lane & 3) * 8;
    const short* gA0 = &A[(m0 + w*32      + lrow) * K + lcol];
    const short* gA1 = &A[(m0 + w*32 + 16 + lrow) * K + lcol];
    const short* gB0 = &B[(n0 + w*16 + lrow) * K + lcol];
    short* lA0 = &As[w*32][0];
    short* lA1 = &As[w*32 + 16][0];
    short* lB0 = &Bs[w*16][0];

    for (int k0 = 0; k0 < K; k0 += 32) {
        __syncthreads();
        async_lds16(gA0 + k0, lA0);
        async_lds16(gA1 + k0, lA1);
        async_lds16(gB0 + k0, lB0);
        __syncthreads();

        s16x8 af[4], bfr[2];
#pragma unroll
        for (int i = 0; i < 4; ++i) af[i]  = *(const s16x8*)&As[wm + i*16 + l16][quad*8];
#pragma unroll
        for (int j = 0; j < 2; ++j) bfr[j] = *(const s16x8*)&Bs[wn + j*16 + l16][quad*8];
#pragma unroll
        for (int i = 0; i < 4; ++i)
#pragma unroll
            for (int j = 0; j < 2; ++j)
                acc[i][j] = mfma16(af[i], bfr[j], acc[i][j]);
    }

#pragma unroll
    for (int j = 0; j < 2; ++j) {
        int n = n0 + wn + j*16 + l16;
        float bi = bf2f(bias[n]);
#pragma unroll
        for (int i = 0; i < 4; ++i) {
#pragma unroll
            for (int r = 0; r < 4; ++r) {
                int m = m0 + wm + i*16 + quad*4 + r;
                out[m * 1024 + n] = acc[i][j][r] + bi;
            }
        }
    }
}

// ---------------------------------------------------------------------------
extern "C" void kernel_launch(void* const* d_in, const int* in_sizes, int n_in,
                              void* d_out, int out_size, void* d_ws, size_t ws_size,
                              hipStream_t stream) {
    float* out = (float*)d_out;
    char* ws = (char*)d_ws;

    const size_t MB = 1u << 20;
    short* xb     = (short*)(ws);            // 8 MB
    short* w_inb  = (short*)(ws + 8*MB);     // 6 MB
    short* b_inb  = (short*)(ws + 14*MB);
    short* w_outb = (short*)(ws + 15*MB);    // 2 MB
    short* b_outb = (short*)(ws + 17*MB);
    short* qb     = (short*)(ws + 18*MB);    // 8 MB [B,H,T,64]
    short* kb     = (short*)(ws + 26*MB);    // 8 MB [B,H,T,64]
    short* vtb    = (short*)(ws + 34*MB);    // 8 MB [B,H,64,T] (direct from gemm)
    short* ctxb   = (short*)(ws + 42*MB);    // 8 MB [B,T,D]

    canon_all_kernel<<<(V_TOT + 255) / 256, 256, 0, stream>>>(
        (const float*)d_in[0], (const float*)d_in[1], (const float*)d_in[2],
        (const float*)d_in[3], (const float*)d_in[4],
        xb, w_inb, b_inb, w_outb, b_outb);

    gemm_qkv_kernel<<<dim3(32, 24), 256, 0, stream>>>(xb, w_inb, b_inb, qb, kb, vtb);
    attn_kernel<<<dim3(32, 32), 256, 0, stream>>>(qb, kb, vtb, ctxb);
    gemm_out_kernel<<<dim3(32, 16), 256, 0, stream>>>(ctxb, w_outb, b_outb, out);
}

// Round 8
// 173.683 us; speedup vs baseline: 1.0657x; 1.0099x over previous
//
#include <hip/hip_runtime.h>

// ---------------------------------------------------------------------------
// Causal MHSA. B=2, T=2048, D=1024, H=16, hd=64. fp32 in -> bf16 internal ->
// fp32 out. R19: attn pairs q-tiles (j, 31-j) in ONE 512-thread block —
// waves 0-3 compute tile A=j, waves 4-7 tile B=31-j CONCURRENTLY over a
// single shared K/V staging loop (R12's sharing without its residency loss:
// 512 blocks x 8 waves x 36KB LDS = 2 blocks/CU = 16 waves/CU, same as R11).
// Stagings/barriers per bh: 528 -> 392 (-26%); uniform 33 units/block.
// GEMMs/canon = R16 exact (128^2 m97 structure is the proven local optimum).
// ---------------------------------------------------------------------------

#define T_SEQ 2048
#define D_MODEL 1024
#define NEG_BIG (-1.0e30f)
#define Q_SCALE 0.18033688f   // 0.125 * log2(e): attention uses exp2 directly

typedef float f32x4 __attribute__((ext_vector_type(4)));
typedef short s16x8 __attribute__((ext_vector_type(8)));
typedef __bf16 bf16x8 __attribute__((ext_vector_type(8)));

__device__ __forceinline__ f32x4 mfma16(s16x8 a, s16x8 b, f32x4 c) {
    // C[m][n]=sum_k A[m][k]B[n][k]; lane: a=A[m=l16][k=quad*8+j],
    // b=B[n=l16][k=quad*8+j]; C: col(l16)=n, row(quad*4+r)=m
    return __builtin_amdgcn_mfma_f32_16x16x32_bf16(
        __builtin_bit_cast(bf16x8, a), __builtin_bit_cast(bf16x8, b), c, 0, 0, 0);
}

__device__ __forceinline__ short f2bf(float f) {          // RNE
    unsigned int u = __float_as_uint(f);
    u += 0x7fffu + ((u >> 16) & 1u);
    return (short)(u >> 16);
}
__device__ __forceinline__ float bf2f(short s) {
    return __uint_as_float(((unsigned int)(unsigned short)s) << 16);
}
__device__ __forceinline__ unsigned cvt_pk_bf16(float lo, float hi) {
    unsigned r;
    asm("v_cvt_pk_bf16_f32 %0, %1, %2" : "=v"(r) : "v"(lo), "v"(hi));
    return r;
}

__device__ __forceinline__ void async_lds16(const short* g, short* l) {
    __builtin_amdgcn_global_load_lds(
        (const __attribute__((address_space(1))) unsigned int*)g,
        (__attribute__((address_space(3))) unsigned int*)l, 16, 0, 0);
}

// ---------------------------------------------------------------------------
// Fused canon: five fp32 inputs -> bf16, float4-vectorized, one launch.
// ---------------------------------------------------------------------------
#define N_X   4194304
#define N_WI  3145728
#define N_BI  3072
#define N_WO  1048576
#define N_BO  1024
#define V_X   (N_X  / 4)
#define V_WI  (N_WI / 4)
#define V_BI  (N_BI / 4)
#define V_WO  (N_WO / 4)
#define V_BO  (N_BO / 4)
#define V_TOT (V_X + V_WI + V_BI + V_WO + V_BO)

__global__ __launch_bounds__(256) void canon_all_kernel(
    const float* __restrict__ x, const float* __restrict__ wi,
    const float* __restrict__ bi, const float* __restrict__ wo,
    const float* __restrict__ bo,
    short* __restrict__ xb, short* __restrict__ wib, short* __restrict__ bib,
    short* __restrict__ wob, short* __restrict__ bob)
{
    int i = blockIdx.x * 256 + threadIdx.x;
    if (i >= V_TOT) return;
    const float* src; short* dst; int off;
    if      (i < V_X)                    { src = x;  dst = xb;  off = i; }
    else if (i < V_X+V_WI)               { src = wi; dst = wib; off = i - V_X; }
    else if (i < V_X+V_WI+V_BI)          { src = bi; dst = bib; off = i - V_X - V_WI; }
    else if (i < V_X+V_WI+V_BI+V_WO)     { src = wo; dst = wob; off = i - V_X - V_WI - V_BI; }
    else                                 { src = bo; dst = bob; off = i - V_X - V_WI - V_BI - V_WO; }
    float4 v = ((const float4*)src)[off];
    short4 o = { f2bf(v.x), f2bf(v.y), f2bf(v.z), f2bf(v.w) };
    ((short4*)dst)[off] = o;
}

// ---------------------------------------------------------------------------
// GEMM1 (m97 structure, BK=32): qkv = x @ w_in^T + b_in.
// q(xQ_SCALE)/k -> [B,H,T,64]; v -> Vt [B,H,64,T] (transpose fused: the
// r-loop's 4 acc values are t-consecutive -> one aligned short4 store).
// ---------------------------------------------------------------------------
__global__ __launch_bounds__(256) void gemm_qkv_kernel(
    const short* __restrict__ A, const short* __restrict__ B,
    const short* __restrict__ bias,
    short* __restrict__ qo, short* __restrict__ ko, short* __restrict__ vto)
{
    const int K = 1024;
    alignas(16) __shared__ short As[128][32];
    alignas(16) __shared__ short Bs[128][32];
    const int m0 = blockIdx.x * 128;
    const int n0 = blockIdx.y * 128;
    const int tid = threadIdx.x;
    const int lane = tid & 63;
    const int w = tid >> 6;
    const int wm = (w >> 1) * 64, wn = (w & 1) * 64;
    const int quad = lane >> 4, l16 = lane & 15;

    f32x4 acc[4][4];
    const f32x4 zero = {0.f, 0.f, 0.f, 0.f};
#pragma unroll
    for (int i = 0; i < 4; ++i)
#pragma unroll
        for (int j = 0; j < 4; ++j) acc[i][j] = zero;

    const int lrow = lane >> 2;
    const int lcol = (lane & 3) * 8;
    const short* gA0 = &A[(m0 + w*32      + lrow) * K + lcol];
    const short* gA1 = &A[(m0 + w*32 + 16 + lrow) * K + lcol];
    const short* gB0 = &B[(n0 + w*32      + lrow) * K + lcol];
    const short* gB1 = &B[(n0 + w*32 + 16 + lrow) * K + lcol];
    short* lA0 = &As[w*32][0];
    short* lA1 = &As[w*32 + 16][0];
    short* lB0 = &Bs[w*32][0];
    short* lB1 = &Bs[w*32 + 16][0];

    for (int k0 = 0; k0 < K; k0 += 32) {
        __syncthreads();
        async_lds16(gA0 + k0, lA0);
        async_lds16(gA1 + k0, lA1);
        async_lds16(gB0 + k0, lB0);
        async_lds16(gB1 + k0, lB1);
        __syncthreads();

        s16x8 af[4], bfr[4];
#pragma unroll
        for (int i = 0; i < 4; ++i) af[i]  = *(const s16x8*)&As[wm + i*16 + l16][quad*8];
#pragma unroll
        for (int j = 0; j < 4; ++j) bfr[j] = *(const s16x8*)&Bs[wn + j*16 + l16][quad*8];
#pragma unroll
        for (int i = 0; i < 4; ++i)
#pragma unroll
            for (int j = 0; j < 4; ++j)
                acc[i][j] = mfma16(af[i], bfr[j], acc[i][j]);
    }

#pragma unroll
    for (int j = 0; j < 4; ++j) {
        int n = n0 + wn + j*16 + l16;
        float bi = bf2f(bias[n]);
        int which = n >> 10;            // wave-uniform (16 consecutive n)
        int h = (n >> 6) & 15, d = n & 63;
        if (which < 2) {                // Q / K: [B,H,T,64]
            short* dst = (which == 0) ? qo : ko;
            float scl = (which == 0) ? Q_SCALE : 1.0f;
#pragma unroll
            for (int i = 0; i < 4; ++i) {
#pragma unroll
                for (int r = 0; r < 4; ++r) {
                    int m = m0 + wm + i*16 + quad*4 + r;
                    int b = m >> 11, t = m & 2047;
                    float v = (acc[i][j][r] + bi) * scl;
                    dst[(((b*16 + h) * 2048) + t) * 64 + d] = f2bf(v);
                }
            }
        } else {                        // V: write transposed [B,H,64,T]
#pragma unroll
            for (int i = 0; i < 4; ++i) {
                int m = m0 + wm + i*16 + quad*4;   // t0, %4 == 0
                int b = m >> 11, t0 = m & 2047;
                short4 o4 = { f2bf(acc[i][j][0] + bi), f2bf(acc[i][j][1] + bi),
                              f2bf(acc[i][j][2] + bi), f2bf(acc[i][j][3] + bi) };
                *(short4*)&vto[(((size_t)(b*16 + h) * 64) + d) * 2048 + t0] = o4;
            }
        }
    }
}

// ---------------------------------------------------------------------------
// Flash attention, co-scheduled pair: block (bh, j), 512 threads / 8 waves.
// Waves 0-3 compute q-tile A=j (rows wq*16..), waves 4-7 q-tile B=31-j,
// sharing one K/V staging loop over s0=0..qbaseB. All guards wave-uniform.
// Per-block compute = (j+1)+(32-j) = 33 tile-units, uniform across grid.
// XCD locality: blockIdx.x = bh (XCD=bh%8, as R11).
// ---------------------------------------------------------------------------
__global__ __launch_bounds__(512) void attn_kernel(
    const short* __restrict__ Q, const short* __restrict__ K,
    const short* __restrict__ Vt, short* __restrict__ ctx)
{
    alignas(16) __shared__ short Ks[64][72];      // [s][d]
    alignas(16) __shared__ short Vs[64][72];      // [d][s]
    alignas(16) __shared__ short Pl[8][16][72];   // per-wave [q][s]

    const int bh = blockIdx.x;                    // 0..31
    const int j  = blockIdx.y;                    // 0..15
    const int tid = threadIdx.x;                  // 0..511
    const int w = tid >> 6, lane = tid & 63;
    const int quad = lane >> 4, l16 = lane & 15;
    const int b = bh >> 4, h = bh & 15;

    const int isB = w >> 2;                       // wave-uniform: 0=tile A, 1=tile B
    const int wq  = w & 3;                        // 16-row group within own tile
    const int qt  = isB ? (31 - j) : j;
    const int qbase  = qt * 64;
    const int qbaseA = j * 64;
    const int qbaseB = (31 - j) * 64;             // block-uniform loop bound

    const short* Qb  = Q  + bh * T_SEQ * 64;
    const short* Kb  = K  + bh * T_SEQ * 64;
    const short* Vbt = Vt + (size_t)bh * 64 * T_SEQ;

    const int qg = qbase + wq*16 + l16;
    const short* qrow = Qb + qg * 64;
    const s16x8 qa0 = *(const s16x8*)(qrow + quad*8);
    const s16x8 qa1 = *(const s16x8*)(qrow + 32 + quad*8);

    const f32x4 zero = {0.f, 0.f, 0.f, 0.f};
    f32x4 o[4];
#pragma unroll
    for (int dt = 0; dt < 4; ++dt) o[dt] = zero;
    float lsum = 0.f;

    // staging: 512 threads, one float4 of K + one of V each
    const int sr  = tid >> 3;                     // 0..63
    const int scl = (tid & 7) * 8;                // 0..56

    // preload tile s0=0
    float4 kf = *(const float4*)&Kb[sr * 64 + scl];
    float4 vf = *(const float4*)&Vbt[(size_t)sr * T_SEQ + scl];

    for (int s0 = 0; s0 <= qbaseB; s0 += 64) {
        __syncthreads();
        *(float4*)&Ks[sr][scl] = kf;
        *(float4*)&Vs[sr][scl] = vf;
        __syncthreads();

        if (s0 + 64 <= qbaseB) {                  // prefetch next tile
            kf = *(const float4*)&Kb[(s0 + 64 + sr) * 64 + scl];
            vf = *(const float4*)&Vbt[(size_t)sr * T_SEQ + s0 + 64 + scl];
        }

        const bool act = isB || (s0 <= qbaseA);   // wave-uniform
        if (act) {
            // S^T = K Q^T
#pragma unroll
            for (int sub = 0; sub < 4; ++sub) {
                s16x8 ka0 = *(const s16x8*)&Ks[sub*16 + l16][quad*8];
                s16x8 ka1 = *(const s16x8*)&Ks[sub*16 + l16][32 + quad*8];
                __builtin_amdgcn_s_setprio(1);
                f32x4 S = mfma16(ka1, qa1, mfma16(ka0, qa0, zero));
                __builtin_amdgcn_s_setprio(0);
                if (s0 == qbase) {                // diagonal: causal mask
                    int sb = s0 + sub*16 + quad*4;
#pragma unroll
                    for (int r = 0; r < 4; ++r)
                        if (sb + r > qg) S[r] = NEG_BIG;
                }
                float p0 = exp2f(S[0]), p1 = exp2f(S[1]);
                float p2 = exp2f(S[2]), p3 = exp2f(S[3]);
                lsum += (p0 + p1) + (p2 + p3);
                uint2 pk;
                pk.x = cvt_pk_bf16(p0, p1);
                pk.y = cvt_pk_bf16(p2, p3);
                *(uint2*)&Pl[w][l16][sub*16 + quad*4] = pk;
            }
            // wave-private Pl: in-order within wave, no barrier

            // O^T += V^T P^T
            s16x8 pb0 = *(const s16x8*)&Pl[w][l16][quad*8];
            s16x8 pb1 = *(const s16x8*)&Pl[w][l16][32 + quad*8];
            __builtin_amdgcn_s_setprio(1);
#pragma unroll
            for (int dt = 0; dt < 4; ++dt) {
                s16x8 va0 = *(const s16x8*)&Vs[dt*16 + l16][quad*8];
                s16x8 va1 = *(const s16x8*)&Vs[dt*16 + l16][32 + quad*8];
                o[dt] = mfma16(va1, pb1, mfma16(va0, pb0, o[dt]));
            }
            __builtin_amdgcn_s_setprio(0);
        }
    }

    lsum += __shfl_xor(lsum, 16, 64);
    lsum += __shfl_xor(lsum, 32, 64);
    float inv = 1.0f / lsum;
    int base = (b * T_SEQ + qg) * D_MODEL + h * 64;
#pragma unroll
    for (int dt = 0; dt < 4; ++dt) {
        uint2 pk;
        pk.x = cvt_pk_bf16(o[dt][0] * inv, o[dt][1] * inv);
        pk.y = cvt_pk_bf16(o[dt][2] * inv, o[dt][3] * inv);
        *(uint2*)&ctx[base + dt*16 + quad*4] = pk;
    }
}

// ---------------------------------------------------------------------------
// GEMM2 (BK=32): out = ctx @ w_out^T + b_out, fp32 store. 128x64, 512 blocks.
// ---------------------------------------------------------------------------
__global__ __launch_bounds__(256) void gemm_out_kernel(
    const short* __restrict__ A, const short* __restrict__ B,
    const short* __restrict__ bias, float* __restrict__ out)
{
    const int K = 1024;
    alignas(16) __shared__ short As[128][32];
    alignas(16) __shared__ short Bs[64][32];
    const int m0 = blockIdx.x * 128;
    const int n0 = blockIdx.y * 64;
    const int tid = threadIdx.x;
    const int lane = tid & 63;
    const int w = tid >> 6;
    const int wm = (w >> 1) * 64, wn = (w & 1) * 32;
    const int quad = lane >> 4, l16 = lane & 15;

    f32x4 acc[4][2];
    const f32x4 zero = {0.f, 0.f, 0.f, 0.f};
#pragma unroll
    for (int i = 0; i < 4; ++i)
#pragma unroll
        for (int j = 0; j < 2; ++j) acc[i][j] = zero;

    const int lrow = lane >> 2;
    const int lcol = (lane & 3) * 8;
    const short* gA0 = &A[(m0 + w*32      + lrow) * K + lcol];
    const short* gA1 = &A[(m0 + w*32 + 16 + lrow) * K + lcol];
    const short* gB0 = &B[(n0 + w*16 + lrow) * K + lcol];
    short* lA0 = &As[w*32][0];
    short* lA1 = &As[w*32 + 16][0];
    short* lB0 = &Bs[w*16][0];

    for (int k0 = 0; k0 < K; k0 += 32) {
        __syncthreads();
        async_lds16(gA0 + k0, lA0);
        async_lds16(gA1 + k0, lA1);
        async_lds16(gB0 + k0, lB0);
        __syncthreads();

        s16x8 af[4], bfr[2];
#pragma unroll
        for (int i = 0; i < 4; ++i) af[i]  = *(const s16x8*)&As[wm + i*16 + l16][quad*8];
#pragma unroll
        for (int j = 0; j < 2; ++j) bfr[j] = *(const s16x8*)&Bs[wn + j*16 + l16][quad*8];
#pragma unroll
        for (int i = 0; i < 4; ++i)
#pragma unroll
            for (int j = 0; j < 2; ++j)
                acc[i][j] = mfma16(af[i], bfr[j], acc[i][j]);
    }

#pragma unroll
    for (int j = 0; j < 2; ++j) {
        int n = n0 + wn + j*16 + l16;
        float bi = bf2f(bias[n]);
#pragma unroll
        for (int i = 0; i < 4; ++i) {
#pragma unroll
            for (int r = 0; r < 4; ++r) {
                int m = m0 + wm + i*16 + quad*4 + r;
                out[m * 1024 + n] = acc[i][j][r] + bi;
            }
        }
    }
}

// ---------------------------------------------------------------------------
extern "C" void kernel_launch(void* const* d_in, const int* in_sizes, int n_in,
                              void* d_out, int out_size, void* d_ws, size_t ws_size,
                              hipStream_t stream) {
    float* out = (float*)d_out;
    char* ws = (char*)d_ws;

    const size_t MB = 1u << 20;
    short* xb     = (short*)(ws);            // 8 MB
    short* w_inb  = (short*)(ws + 8*MB);     // 6 MB
    short* b_inb  = (short*)(ws + 14*MB);
    short* w_outb = (short*)(ws + 15*MB);    // 2 MB
    short* b_outb = (short*)(ws + 17*MB);
    short* qb     = (short*)(ws + 18*MB);    // 8 MB [B,H,T,64]
    short* kb     = (short*)(ws + 26*MB);    // 8 MB [B,H,T,64]
    short* vtb    = (short*)(ws + 34*MB);    // 8 MB [B,H,64,T] (direct from gemm)
    short* ctxb   = (short*)(ws + 42*MB);    // 8 MB [B,T,D]

    canon_all_kernel<<<(V_TOT + 255) / 256, 256, 0, stream>>>(
        (const float*)d_in[0], (const float*)d_in[1], (const float*)d_in[2],
        (const float*)d_in[3], (const float*)d_in[4],
        xb, w_inb, b_inb, w_outb, b_outb);

    gemm_qkv_kernel<<<dim3(32, 24), 256, 0, stream>>>(xb, w_inb, b_inb, qb, kb, vtb);
    attn_kernel<<<dim3(32, 16), 512, 0, stream>>>(qb, kb, vtb, ctxb);
    gemm_out_kernel<<<dim3(32, 16), 256, 0, stream>>>(ctxb, w_outb, b_outb, out);
}

// Round 9
// 171.215 us; speedup vs baseline: 1.0810x; 1.0144x over previous
//
#include <hip/hip_runtime.h>

// ---------------------------------------------------------------------------
// Causal MHSA. B=2, T=2048, D=1024, H=16, hd=64. fp32 in -> bf16 internal ->
// fp32 out. R20: attn = R19 paired-tile skeleton with (1) K/V staging via
// global_load_lds into double-buffered UNPADDED [64][64] tiles, one barrier
// per tile (was reg-stage + 2 barriers); (2) XOR swizzle pair: pre-swizzled
// global source chunk (l&7)^(l>>3) + swizzled fragment reads col^((row&7)*8)
// (rule 21: linear LDS dest); (3) softmax denominator via MFMA against a
// bf16-ones fragment (kills 16 VALU adds/unit + final shuffles).
// GEMMs/canon = R16 exact.
// ---------------------------------------------------------------------------

#define T_SEQ 2048
#define D_MODEL 1024
#define NEG_BIG (-1.0e30f)
#define Q_SCALE 0.18033688f   // 0.125 * log2(e): attention uses exp2 directly

typedef float f32x4 __attribute__((ext_vector_type(4)));
typedef short s16x8 __attribute__((ext_vector_type(8)));
typedef __bf16 bf16x8 __attribute__((ext_vector_type(8)));

__device__ __forceinline__ f32x4 mfma16(s16x8 a, s16x8 b, f32x4 c) {
    // C[m][n]=sum_k A[m][k]B[n][k]; lane: a=A[m=l16][k=quad*8+j],
    // b=B[n=l16][k=quad*8+j]; C: col(l16)=n, row(quad*4+r)=m
    return __builtin_amdgcn_mfma_f32_16x16x32_bf16(
        __builtin_bit_cast(bf16x8, a), __builtin_bit_cast(bf16x8, b), c, 0, 0, 0);
}

__device__ __forceinline__ short f2bf(float f) {          // RNE
    unsigned int u = __float_as_uint(f);
    u += 0x7fffu + ((u >> 16) & 1u);
    return (short)(u >> 16);
}
__device__ __forceinline__ float bf2f(short s) {
    return __uint_as_float(((unsigned int)(unsigned short)s) << 16);
}
__device__ __forceinline__ unsigned cvt_pk_bf16(float lo, float hi) {
    unsigned r;
    asm("v_cvt_pk_bf16_f32 %0, %1, %2" : "=v"(r) : "v"(lo), "v"(hi));
    return r;
}

__device__ __forceinline__ void async_lds16(const short* g, short* l) {
    __builtin_amdgcn_global_load_lds(
        (const __attribute__((address_space(1))) unsigned int*)g,
        (__attribute__((address_space(3))) unsigned int*)l, 16, 0, 0);
}

// ---------------------------------------------------------------------------
// Fused canon: five fp32 inputs -> bf16, float4-vectorized, one launch.
// ---------------------------------------------------------------------------
#define N_X   4194304
#define N_WI  3145728
#define N_BI  3072
#define N_WO  1048576
#define N_BO  1024
#define V_X   (N_X  / 4)
#define V_WI  (N_WI / 4)
#define V_BI  (N_BI / 4)
#define V_WO  (N_WO / 4)
#define V_BO  (N_BO / 4)
#define V_TOT (V_X + V_WI + V_BI + V_WO + V_BO)

__global__ __launch_bounds__(256) void canon_all_kernel(
    const float* __restrict__ x, const float* __restrict__ wi,
    const float* __restrict__ bi, const float* __restrict__ wo,
    const float* __restrict__ bo,
    short* __restrict__ xb, short* __restrict__ wib, short* __restrict__ bib,
    short* __restrict__ wob, short* __restrict__ bob)
{
    int i = blockIdx.x * 256 + threadIdx.x;
    if (i >= V_TOT) return;
    const float* src; short* dst; int off;
    if      (i < V_X)                    { src = x;  dst = xb;  off = i; }
    else if (i < V_X+V_WI)               { src = wi; dst = wib; off = i - V_X; }
    else if (i < V_X+V_WI+V_BI)          { src = bi; dst = bib; off = i - V_X - V_WI; }
    else if (i < V_X+V_WI+V_BI+V_WO)     { src = wo; dst = wob; off = i - V_X - V_WI - V_BI; }
    else                                 { src = bo; dst = bob; off = i - V_X - V_WI - V_BI - V_WO; }
    float4 v = ((const float4*)src)[off];
    short4 o = { f2bf(v.x), f2bf(v.y), f2bf(v.z), f2bf(v.w) };
    ((short4*)dst)[off] = o;
}

// ---------------------------------------------------------------------------
// GEMM1 (m97 structure, BK=32): qkv = x @ w_in^T + b_in.
// q(xQ_SCALE)/k -> [B,H,T,64]; v -> Vt [B,H,64,T] (transpose fused).
// ---------------------------------------------------------------------------
__global__ __launch_bounds__(256) void gemm_qkv_kernel(
    const short* __restrict__ A, const short* __restrict__ B,
    const short* __restrict__ bias,
    short* __restrict__ qo, short* __restrict__ ko, short* __restrict__ vto)
{
    const int K = 1024;
    alignas(16) __shared__ short As[128][32];
    alignas(16) __shared__ short Bs[128][32];
    const int m0 = blockIdx.x * 128;
    const int n0 = blockIdx.y * 128;
    const int tid = threadIdx.x;
    const int lane = tid & 63;
    const int w = tid >> 6;
    const int wm = (w >> 1) * 64, wn = (w & 1) * 64;
    const int quad = lane >> 4, l16 = lane & 15;

    f32x4 acc[4][4];
    const f32x4 zero = {0.f, 0.f, 0.f, 0.f};
#pragma unroll
    for (int i = 0; i < 4; ++i)
#pragma unroll
        for (int j = 0; j < 4; ++j) acc[i][j] = zero;

    const int lrow = lane >> 2;
    const int lcol = (lane & 3) * 8;
    const short* gA0 = &A[(m0 + w*32      + lrow) * K + lcol];
    const short* gA1 = &A[(m0 + w*32 + 16 + lrow) * K + lcol];
    const short* gB0 = &B[(n0 + w*32      + lrow) * K + lcol];
    const short* gB1 = &B[(n0 + w*32 + 16 + lrow) * K + lcol];
    short* lA0 = &As[w*32][0];
    short* lA1 = &As[w*32 + 16][0];
    short* lB0 = &Bs[w*32][0];
    short* lB1 = &Bs[w*32 + 16][0];

    for (int k0 = 0; k0 < K; k0 += 32) {
        __syncthreads();
        async_lds16(gA0 + k0, lA0);
        async_lds16(gA1 + k0, lA1);
        async_lds16(gB0 + k0, lB0);
        async_lds16(gB1 + k0, lB1);
        __syncthreads();

        s16x8 af[4], bfr[4];
#pragma unroll
        for (int i = 0; i < 4; ++i) af[i]  = *(const s16x8*)&As[wm + i*16 + l16][quad*8];
#pragma unroll
        for (int j = 0; j < 4; ++j) bfr[j] = *(const s16x8*)&Bs[wn + j*16 + l16][quad*8];
#pragma unroll
        for (int i = 0; i < 4; ++i)
#pragma unroll
            for (int j = 0; j < 4; ++j)
                acc[i][j] = mfma16(af[i], bfr[j], acc[i][j]);
    }

#pragma unroll
    for (int j = 0; j < 4; ++j) {
        int n = n0 + wn + j*16 + l16;
        float bi = bf2f(bias[n]);
        int which = n >> 10;            // wave-uniform (16 consecutive n)
        int h = (n >> 6) & 15, d = n & 63;
        if (which < 2) {                // Q / K: [B,H,T,64]
            short* dst = (which == 0) ? qo : ko;
            float scl = (which == 0) ? Q_SCALE : 1.0f;
#pragma unroll
            for (int i = 0; i < 4; ++i) {
#pragma unroll
                for (int r = 0; r < 4; ++r) {
                    int m = m0 + wm + i*16 + quad*4 + r;
                    int b = m >> 11, t = m & 2047;
                    float v = (acc[i][j][r] + bi) * scl;
                    dst[(((b*16 + h) * 2048) + t) * 64 + d] = f2bf(v);
                }
            }
        } else {                        // V: write transposed [B,H,64,T]
#pragma unroll
            for (int i = 0; i < 4; ++i) {
                int m = m0 + wm + i*16 + quad*4;   // t0, %4 == 0
                int b = m >> 11, t0 = m & 2047;
                short4 o4 = { f2bf(acc[i][j][0] + bi), f2bf(acc[i][j][1] + bi),
                              f2bf(acc[i][j][2] + bi), f2bf(acc[i][j][3] + bi) };
                *(short4*)&vto[(((size_t)(b*16 + h) * 64) + d) * 2048 + t0] = o4;
            }
        }
    }
}

// ---------------------------------------------------------------------------
// Flash attention, paired q-tiles (R19) + gload_lds dbuf K/V + swizzle +
// MFMA-lsum. Block (bh, j), 512 threads / 8 waves: waves 0-3 tile A=j,
// waves 4-7 tile B=31-j. Staging: wave w gload_lds rows w*8..w*8+7 of K and
// V tile; LDS dest linear, global source pre-swizzled chunk (l&7)^(l>>3);
// fragment reads swizzled col ^ ((row&7)*8). One __syncthreads per tile.
// ---------------------------------------------------------------------------
__global__ __launch_bounds__(512) void attn_kernel(
    const short* __restrict__ Q, const short* __restrict__ K,
    const short* __restrict__ Vt, short* __restrict__ ctx)
{
    alignas(16) __shared__ short Ks2[2][64][64];   // [buf][s][d], swizzled
    alignas(16) __shared__ short Vs2[2][64][64];   // [buf][d][s], swizzled
    alignas(16) __shared__ short Pl[8][16][72];    // per-wave [q][s]

    const int bh = blockIdx.x;                    // 0..31
    const int j  = blockIdx.y;                    // 0..15
    const int tid = threadIdx.x;                  // 0..511
    const int w = tid >> 6, lane = tid & 63;
    const int quad = lane >> 4, l16 = lane & 15;
    const int b = bh >> 4, h = bh & 15;

    const int isB = w >> 2;                       // wave-uniform: 0=tile A, 1=tile B
    const int wq  = w & 3;                        // 16-row group within own tile
    const int qt  = isB ? (31 - j) : j;
    const int qbase  = qt * 64;
    const int qbaseA = j * 64;
    const int qbaseB = (31 - j) * 64;             // block-uniform loop bound

    const short* Qb  = Q  + bh * T_SEQ * 64;
    const short* Kb  = K  + bh * T_SEQ * 64;
    const short* Vbt = Vt + (size_t)bh * 64 * T_SEQ;

    const int qg = qbase + wq*16 + l16;
    const short* qrow = Qb + qg * 64;
    const s16x8 qa0 = *(const s16x8*)(qrow + quad*8);
    const s16x8 qa1 = *(const s16x8*)(qrow + 32 + quad*8);

    const s16x8 ones = { (short)0x3F80, (short)0x3F80, (short)0x3F80, (short)0x3F80,
                         (short)0x3F80, (short)0x3F80, (short)0x3F80, (short)0x3F80 };

    const f32x4 zero = {0.f, 0.f, 0.f, 0.f};
    f32x4 o[4];
#pragma unroll
    for (int dt = 0; dt < 4; ++dt) o[dt] = zero;
    f32x4 ls = zero;                              // MFMA-accumulated lsum

    // staging geometry: wave w covers rows w*8..w*8+7 (1KB per gload instr)
    const int srow   = w*8 + (lane >> 3);                    // row this lane covers
    const int schunk = ((lane & 7) ^ (lane >> 3)) * 8;       // pre-swizzled col (shorts)
    short* kdst0 = &Ks2[0][w*8][0];               // wave-uniform linear dests
    short* kdst1 = &Ks2[1][w*8][0];
    short* vdst0 = &Vs2[0][w*8][0];
    short* vdst1 = &Vs2[1][w*8][0];

    const int csw = (l16 & 7) * 8;                // fragment-read swizzle (shorts)

    // prologue: issue tile s0=0 into buf 0
    async_lds16(&Kb[srow * 64 + schunk], kdst0);
    async_lds16(&Vbt[(size_t)srow * T_SEQ + schunk], vdst0);

    int cur = 0;
    for (int s0 = 0; s0 <= qbaseB; s0 += 64) {
        __syncthreads();   // drains own gloads for tile s0; publishes; closes old reads

        if (s0 + 64 <= qbaseB) {                  // issue next tile into cur^1
            async_lds16(&Kb[(s0 + 64 + srow) * 64 + schunk], cur ? kdst0 : kdst1);
            async_lds16(&Vbt[(size_t)srow * T_SEQ + s0 + 64 + schunk], cur ? vdst0 : vdst1);
        }

        const bool act = isB || (s0 <= qbaseA);   // wave-uniform
        if (act) {
            // S^T = K Q^T
#pragma unroll
            for (int sub = 0; sub < 4; ++sub) {
                s16x8 ka0 = *(const s16x8*)&Ks2[cur][sub*16 + l16][(quad*8) ^ csw];
                s16x8 ka1 = *(const s16x8*)&Ks2[cur][sub*16 + l16][(32 + quad*8) ^ csw];
                __builtin_amdgcn_s_setprio(1);
                f32x4 S = mfma16(ka1, qa1, mfma16(ka0, qa0, zero));
                __builtin_amdgcn_s_setprio(0);
                if (s0 == qbase) {                // diagonal: causal mask
                    int sb = s0 + sub*16 + quad*4;
#pragma unroll
                    for (int r = 0; r < 4; ++r)
                        if (sb + r > qg) S[r] = NEG_BIG;
                }
                float p0 = exp2f(S[0]), p1 = exp2f(S[1]);
                float p2 = exp2f(S[2]), p3 = exp2f(S[3]);
                uint2 pk;
                pk.x = cvt_pk_bf16(p0, p1);
                pk.y = cvt_pk_bf16(p2, p3);
                *(uint2*)&Pl[w][l16][sub*16 + quad*4] = pk;
            }
            // wave-private Pl: in-order within wave, no barrier

            // O^T += V^T P^T ; lsum via ones-fragment MFMA
            s16x8 pb0 = *(const s16x8*)&Pl[w][l16][quad*8];
            s16x8 pb1 = *(const s16x8*)&Pl[w][l16][32 + quad*8];
            __builtin_amdgcn_s_setprio(1);
            ls = mfma16(ones, pb1, mfma16(ones, pb0, ls));
#pragma unroll
            for (int dt = 0; dt < 4; ++dt) {
                s16x8 va0 = *(const s16x8*)&Vs2[cur][dt*16 + l16][(quad*8) ^ csw];
                s16x8 va1 = *(const s16x8*)&Vs2[cur][dt*16 + l16][(32 + quad*8) ^ csw];
                o[dt] = mfma16(va1, pb1, mfma16(va0, pb0, o[dt]));
            }
            __builtin_amdgcn_s_setprio(0);
        }
        cur ^= 1;
    }

    float inv = 1.0f / ls[0];                     // all acc rows equal (ones A-frag)
    int base = (b * T_SEQ + qg) * D_MODEL + h * 64;
#pragma unroll
    for (int dt = 0; dt < 4; ++dt) {
        uint2 pk;
        pk.x = cvt_pk_bf16(o[dt][0] * inv, o[dt][1] * inv);
        pk.y = cvt_pk_bf16(o[dt][2] * inv, o[dt][3] * inv);
        *(uint2*)&ctx[base + dt*16 + quad*4] = pk;
    }
}

// ---------------------------------------------------------------------------
// GEMM2 (BK=32): out = ctx @ w_out^T + b_out, fp32 store. 128x64, 512 blocks.
// ---------------------------------------------------------------------------
__global__ __launch_bounds__(256) void gemm_out_kernel(
    const short* __restrict__ A, const short* __restrict__ B,
    const short* __restrict__ bias, float* __restrict__ out)
{
    const int K = 1024;
    alignas(16) __shared__ short As[128][32];
    alignas(16) __shared__ short Bs[64][32];
    const int m0 = blockIdx.x * 128;
    const int n0 = blockIdx.y * 64;
    const int tid = threadIdx.x;
    const int lane = tid & 63;
    const int w = tid >> 6;
    const int wm = (w >> 1) * 64, wn = (w & 1) * 32;
    const int quad = lane >> 4, l16 = lane & 15;

    f32x4 acc[4][2];
    const f32x4 zero = {0.f, 0.f, 0.f, 0.f};
#pragma unroll
    for (int i = 0; i < 4; ++i)
#pragma unroll
        for (int j = 0; j < 2; ++j) acc[i][j] = zero;

    const int lrow = lane >> 2;
    const int lcol = (lane & 3) * 8;
    const short* gA0 = &A[(m0 + w*32      + lrow) * K + lcol];
    const short* gA1 = &A[(m0 + w*32 + 16 + lrow) * K + lcol];
    const short* gB0 = &B[(n0 + w*16 + lrow) * K + lcol];
    short* lA0 = &As[w*32][0];
    short* lA1 = &As[w*32 + 16][0];
    short* lB0 = &Bs[w*16][0];

    for (int k0 = 0; k0 < K; k0 += 32) {
        __syncthreads();
        async_lds16(gA0 + k0, lA0);
        async_lds16(gA1 + k0, lA1);
        async_lds16(gB0 + k0, lB0);
        __syncthreads();

        s16x8 af[4], bfr[2];
#pragma unroll
        for (int i = 0; i < 4; ++i) af[i]  = *(const s16x8*)&As[wm + i*16 + l16][quad*8];
#pragma unroll
        for (int j = 0; j < 2; ++j) bfr[j] = *(const s16x8*)&Bs[wn + j*16 + l16][quad*8];
#pragma unroll
        for (int i = 0; i < 4; ++i)
#pragma unroll
            for (int j = 0; j < 2; ++j)
                acc[i][j] = mfma16(af[i], bfr[j], acc[i][j]);
    }

#pragma unroll
    for (int j = 0; j < 2; ++j) {
        int n = n0 + wn + j*16 + l16;
        float bi = bf2f(bias[n]);
#pragma unroll
        for (int i = 0; i < 4; ++i) {
#pragma unroll
            for (int r = 0; r < 4; ++r) {
                int m = m0 + wm + i*16 + quad*4 + r;
                out[m * 1024 + n] = acc[i][j][r] + bi;
            }
        }
    }
}

// ---------------------------------------------------------------------------
extern "C" void kernel_launch(void* const* d_in, const int* in_sizes, int n_in,
                              void* d_out, int out_size, void* d_ws, size_t ws_size,
                              hipStream_t stream) {
    float* out = (float*)d_out;
    char* ws = (char*)d_ws;

    const size_t MB = 1u << 20;
    short* xb     = (short*)(ws);            // 8 MB
    short* w_inb  = (short*)(ws + 8*MB);     // 6 MB
    short* b_inb  = (short*)(ws + 14*MB);
    short* w_outb = (short*)(ws + 15*MB);    // 2 MB
    short* b_outb = (short*)(ws + 17*MB);
    short* qb     = (short*)(ws + 18*MB);    // 8 MB [B,H,T,64]
    short* kb     = (short*)(ws + 26*MB);    // 8 MB [B,H,T,64]
    short* vtb    = (short*)(ws + 34*MB);    // 8 MB [B,H,64,T] (direct from gemm)
    short* ctxb   = (short*)(ws + 42*MB);    // 8 MB [B,T,D]

    canon_all_kernel<<<(V_TOT + 255) / 256, 256, 0, stream>>>(
        (const float*)d_in[0], (const float*)d_in[1], (const float*)d_in[2],
        (const float*)d_in[3], (const float*)d_in[4],
        xb, w_inb, b_inb, w_outb, b_outb);

    gemm_qkv_kernel<<<dim3(32, 24), 256, 0, stream>>>(xb, w_inb, b_inb, qb, kb, vtb);
    attn_kernel<<<dim3(32, 16), 512, 0, stream>>>(qb, kb, vtb, ctxb);
    gemm_out_kernel<<<dim3(32, 16), 256, 0, stream>>>(ctxb, w_outb, b_outb, out);
}